// Round 7
// baseline (73.389 us; speedup 1.0000x reference)
//
#include <hip/hip_runtime.h>
#include <hip/hip_bf16.h>
#include <stdint.h>

// Real spherical harmonics basis, degree 4 (l = 0..3), 16 coefficients.
// [B,3] f32 -> [B,16] f32, B = 4194304. Memory-bound streaming map.
//
// Round-7: double-buffered async staging via global_load_lds, 16 B width
// (the HW-validated lane-stride layout; R6's 12 B variant landed data at
// the wrong LDS offsets -> absmax 264).
//  - 2048 blocks x 256 threads; each block owns 8 consecutive 256-pt chunks
//  - per chunk: threads 0..191 (waves 0-2, wave-uniform predicate) each
//    issue ONE 16 B global_load_lds; LDS dest = wave base + lane*16 ->
//    tightly contiguous 3072 B, identical to the linear AoS input layout
//  - stage(chunk k+1) issued BEFORE computing chunk k (HBM latency hides
//    under the 4-store compute phase); one __syncthreads per chunk drains
//    vmcnt (compiler emits s_waitcnt vmcnt(0) before s_barrier)
//  - compute: q = t&3 quarter per thread, xyz from LDS (stride-3 ->
//    conflict-free mod 32, quad same-address broadcast free)
//  - writes perfectly lane-contiguous float4 streams (plain stores;
//    NT stores measured -6 us in R4/R5 A/B).

typedef float f32x4 __attribute__((ext_vector_type(4)));
typedef __attribute__((address_space(3))) uint32_t lds_u32;
typedef const __attribute__((address_space(1))) uint32_t glb_u32;

#define NCH 8   // chunks per block

#define C0    0.28209479177387814f
#define C1    0.48860251190291987f
#define C2_0  1.0925484305920792f
#define C2_2a 0.94617469575755997f
#define C2_2b 0.31539156525251999f
#define C2_4  0.54627421529603959f
#define C3_0  0.59004358992664352f
#define C3_1  2.8906114426405538f
#define C3_2  0.45704579946446572f
#define C3_3  0.3731763325901154f
#define C3_5  1.445305721320277f

__global__ void __launch_bounds__(256) sh_encode_kernel(
    const float* __restrict__ in,          // [B,3]
    const uint32_t* __restrict__ size_raw, // scalar `size` (value 1)
    f32x4* __restrict__ out4)              // [B*4] float4 == [B,16] float
{
    // Decode scalar `size`: int bits or float bits both map to its value.
    uint32_t sb = *size_raw;
    float s = (sb == 0x3F800000u) ? 1.0f : (float)(int)sb;
    float inv = 1.0f / s;

    __shared__ float smem[2][768];         // 2 x 256 points x 3 floats (6 KB)

    int t   = threadIdx.x;
    int wid = t >> 6;                      // wave id 0..3
    size_t chunk0 = (size_t)blockIdx.x * NCH;

    // Async stage chunk -> smem[b]: threads 0..191 load 16 B each.
    // Wave w lanes write smem[b] + w*1024 + lane*16  (tight, linear).
    auto stage = [&](int b, size_t chunk) {
        if (t < 192) {
            glb_u32* g = (glb_u32*)(uintptr_t)(in + chunk * 768 + (size_t)t * 4);
            lds_u32* l = (lds_u32*)(uintptr_t)(&smem[b][wid * 256]);
            __builtin_amdgcn_global_load_lds(g, l, 16 /*bytes*/, 0 /*offset*/, 0 /*aux*/);
        }
    };

    stage(0, chunk0);

    int q     = t & 3;                     // which quarter of the 16 coeffs
    int pbase = t >> 2;                    // point-within-64 group

    for (int it = 0; it < NCH; ++it) {
        int cur = it & 1;
        __syncthreads();                   // vmcnt(0)+barrier: smem[cur] ready,
                                           // smem[cur^1] reads from prev iter fenced
        if (it + 1 < NCH) stage(cur ^ 1, chunk0 + it + 1);

        const float* sp = smem[cur];
        size_t out_base = (chunk0 + it) * 1024 + (size_t)t;

        #pragma unroll
        for (int j = 0; j < 4; ++j) {
            int pl = j * 64 + pbase;       // local point index 0..255
            float x = sp[pl * 3 + 0] * inv;
            float y = sp[pl * 3 + 1] * inv;
            float z = sp[pl * 3 + 2] * inv;

            f32x4 r;
            if (q == 0) {
                r.x = C0;
                r.y = -C1 * y;
                r.z =  C1 * z;
                r.w = -C1 * x;
            } else if (q == 1) {
                float xy = x * y, yz = y * z, xz = x * z, zz = z * z;
                r.x =  C2_0 * xy;
                r.y = -C2_0 * yz;
                r.z =  C2_2a * zz - C2_2b;
                r.w = -C2_0 * xz;
            } else if (q == 2) {
                float xx = x * x, yy = y * y, zz = z * z;
                r.x = C2_4 * (xx - yy);
                r.y = C3_0 * y * (-3.0f * xx + yy);
                r.z = C3_1 * (x * y) * z;
                r.w = C3_2 * y * (1.0f - 5.0f * zz);
            } else {
                float xx = x * x, yy = y * y, zz = z * z;
                r.x = C3_3 * z * (5.0f * zz - 3.0f);
                r.y = C3_2 * x * (1.0f - 5.0f * zz);
                r.z = C3_5 * z * (xx - yy);
                r.w = C3_0 * x * (-xx + 3.0f * yy);
            }
            out4[out_base + (size_t)j * 256] = r;
        }
    }
}

extern "C" void kernel_launch(void* const* d_in, const int* in_sizes, int n_in,
                              void* d_out, int out_size, void* d_ws, size_t ws_size,
                              hipStream_t stream) {
    const float* in = (const float*)d_in[0];
    const uint32_t* size_raw = (const uint32_t*)d_in[1];
    f32x4* out4 = (f32x4*)d_out;

    int B = in_sizes[0] / 3;               // 4194304
    int blocks = B / (256 * NCH);          // 2048 blocks, exact
    sh_encode_kernel<<<blocks, 256, 0, stream>>>(in, size_raw, out4);
}

// Round 8
// 52.219 us; speedup vs baseline: 1.4054x; 1.4054x over previous
//
#include <hip/hip_runtime.h>
#include <hip/hip_bf16.h>
#include <stdint.h>

// Real spherical harmonics basis, degree 4 (l = 0..3), 16 coefficients.
// [B,3] f32 -> [B,16] f32, B = 4194304. Memory-bound streaming map.
//
// Round-8 = round-2 structure (best: 60.7 us) + two micro-levers:
//  - NT hint on STAGING LOADS ONLY (input is stream-once; frees L2
//    retention for the dirty write stream; R4's regression bundled
//    store-NT which defeats write-combining -- loads-only untested)
//  - __launch_bounds__(256, 8): 8 waves/EU occupancy headroom
// Structure: one block per 256-point chunk, 256 threads.
//  - threads 0..191 stage 192 coalesced float4 (3 KB) into LDS
//  - one barrier
//  - each thread writes 4 output float4s (quarter q = t&3), xyz from LDS
//    (stride-3 -> conflict-free mod 32, quad same-address broadcast free)
//  - plain stores (perfectly lane-contiguous float4 streams).

typedef float f32x4 __attribute__((ext_vector_type(4)));

#define C0    0.28209479177387814f
#define C1    0.48860251190291987f
#define C2_0  1.0925484305920792f
#define C2_2a 0.94617469575755997f
#define C2_2b 0.31539156525251999f
#define C2_4  0.54627421529603959f
#define C3_0  0.59004358992664352f
#define C3_1  2.8906114426405538f
#define C3_2  0.45704579946446572f
#define C3_3  0.3731763325901154f
#define C3_5  1.445305721320277f

__global__ void __launch_bounds__(256, 8) sh_encode_kernel(
    const f32x4* __restrict__ in4,         // [B*3/4] float4 view of [B,3]
    const uint32_t* __restrict__ size_raw, // scalar `size` (value 1)
    f32x4* __restrict__ out4)              // [B*4] float4 == [B,16] float
{
    // Decode scalar `size`: int bits or float bits both map to its value.
    uint32_t sb = *size_raw;
    float s = (sb == 0x3F800000u) ? 1.0f : (float)(int)sb;
    float inv = 1.0f / s;

    __shared__ float smem[768];            // 256 points * 3 floats = 3 KB

    int t = threadIdx.x;
    size_t chunk = blockIdx.x;             // one chunk = 256 points

    // Stage input: 192 coalesced float4 NT loads (stream-once data).
    if (t < 192) {
        f32x4 v = __builtin_nontemporal_load(&in4[chunk * 192 + t]);
        reinterpret_cast<f32x4*>(smem)[t] = v;
    }
    __syncthreads();

    int q     = t & 3;                     // which quarter of the 16 coeffs
    int pbase = t >> 2;                    // point-within-64 group
    size_t out_base = chunk * 1024 + (size_t)t;

    #pragma unroll
    for (int j = 0; j < 4; ++j) {
        int pl = j * 64 + pbase;           // local point index 0..255
        float x = smem[pl * 3 + 0] * inv;
        float y = smem[pl * 3 + 1] * inv;
        float z = smem[pl * 3 + 2] * inv;

        f32x4 r;
        if (q == 0) {
            r.x = C0;
            r.y = -C1 * y;
            r.z =  C1 * z;
            r.w = -C1 * x;
        } else if (q == 1) {
            float xy = x * y, yz = y * z, xz = x * z, zz = z * z;
            r.x =  C2_0 * xy;
            r.y = -C2_0 * yz;
            r.z =  C2_2a * zz - C2_2b;
            r.w = -C2_0 * xz;
        } else if (q == 2) {
            float xx = x * x, yy = y * y, zz = z * z;
            r.x = C2_4 * (xx - yy);
            r.y = C3_0 * y * (-3.0f * xx + yy);
            r.z = C3_1 * (x * y) * z;
            r.w = C3_2 * y * (1.0f - 5.0f * zz);
        } else {
            float xx = x * x, yy = y * y, zz = z * z;
            r.x = C3_3 * z * (5.0f * zz - 3.0f);
            r.y = C3_2 * x * (1.0f - 5.0f * zz);
            r.z = C3_5 * z * (xx - yy);
            r.w = C3_0 * x * (-xx + 3.0f * yy);
        }
        out4[out_base + (size_t)j * 256] = r;
    }
}

extern "C" void kernel_launch(void* const* d_in, const int* in_sizes, int n_in,
                              void* d_out, int out_size, void* d_ws, size_t ws_size,
                              hipStream_t stream) {
    const f32x4* in4 = (const f32x4*)d_in[0];
    const uint32_t* size_raw = (const uint32_t*)d_in[1];
    f32x4* out4 = (f32x4*)d_out;

    int B = in_sizes[0] / 3;               // 4194304
    int blocks = B / 256;                  // 16384 chunks, exact
    sh_encode_kernel<<<blocks, 256, 0, stream>>>(in4, size_raw, out4);
}